// Round 2
// baseline (201.567 us; speedup 1.0000x reference)
//
#include <hip/hip_runtime.h>

// GNNIntraAgg: out[b,:] = relu(mean_k features[neigh_ids[b,k], :])
// B=16384, K=32, N=100000, D=256, fp32 in / fp32 out.
//
// One 64-lane wave per batch row; lane i owns float4 #i of the 256-float row
// (64 lanes x 16 B = 1 KB per row, fully coalesced). Every lane loads the
// row's 32 neighbor ids itself via 8 int4 loads (same address across the
// wave -> one L1 transaction each, hardware broadcast). No __shfl, no
// divergent-guarded loads, no LDS: deterministic input-only dataflow.
// Grid-stride over rows with explicit bound so any grid size is correct.

constexpr int K  = 32;
constexpr int D  = 256;
constexpr int D4 = D / 4;   // 64 float4 per feature row == one per lane

__global__ __launch_bounds__(256) void gnn_agg_kernel(
    const int* __restrict__ neigh_ids,    // [B, K]
    const float* __restrict__ features,   // [N, D]
    float* __restrict__ out,              // [B, D]
    int n_rows)
{
    const int waves_per_block = blockDim.x >> 6;
    const int lane = threadIdx.x & 63;
    const int row_stride = gridDim.x * waves_per_block;

    const float4* __restrict__ f4 = reinterpret_cast<const float4*>(features);
    float4* __restrict__ o4 = reinterpret_cast<float4*>(out);

    for (int row = blockIdx.x * waves_per_block + (threadIdx.x >> 6);
         row < n_rows; row += row_stride) {

        // all lanes load all 32 ids (8 x int4; wave-uniform addresses)
        const int4* __restrict__ idp =
            reinterpret_cast<const int4*>(neigh_ids + (size_t)row * K);
        int4 id8[K / 4];
        #pragma unroll
        for (int c = 0; c < K / 4; ++c) id8[c] = idp[c];

        float4 acc = make_float4(0.f, 0.f, 0.f, 0.f);
        #pragma unroll
        for (int c = 0; c < K / 4; ++c) {
            const float4 v0 = f4[(size_t)id8[c].x * D4 + lane];
            const float4 v1 = f4[(size_t)id8[c].y * D4 + lane];
            const float4 v2 = f4[(size_t)id8[c].z * D4 + lane];
            const float4 v3 = f4[(size_t)id8[c].w * D4 + lane];
            acc.x += v0.x + v1.x + v2.x + v3.x;
            acc.y += v0.y + v1.y + v2.y + v3.y;
            acc.z += v0.z + v1.z + v2.z + v3.z;
            acc.w += v0.w + v1.w + v2.w + v3.w;
        }

        const float s = 1.0f / (float)K;
        float4 r;
        r.x = fmaxf(acc.x * s, 0.f);
        r.y = fmaxf(acc.y * s, 0.f);
        r.z = fmaxf(acc.z * s, 0.f);
        r.w = fmaxf(acc.w * s, 0.f);

        o4[(size_t)row * D4 + lane] = r;
    }
}

extern "C" void kernel_launch(void* const* d_in, const int* in_sizes, int n_in,
                              void* d_out, int out_size, void* d_ws, size_t ws_size,
                              hipStream_t stream) {
    const int*   neigh_ids = (const int*)d_in[0];     // [B, K] int32
    const float* features  = (const float*)d_in[1];   // [N, D] fp32
    float*       out       = (float*)d_out;           // [B, D] fp32

    const int n_rows = out_size / D;                  // B = 16384
    const int waves_per_block = 256 / 64;
    const int blocks = (n_rows + waves_per_block - 1) / waves_per_block;

    gnn_agg_kernel<<<blocks, 256, 0, stream>>>(neigh_ids, features, out, n_rows);
}

// Round 3
// 201.431 us; speedup vs baseline: 1.0007x; 1.0007x over previous
//
#include <hip/hip_runtime.h>

// GNNIntraAgg: out[b,:] = relu(mean_k features[neigh_ids[b,k], :])
// B=16384, K=32, N=100000, D=256, fp32.
//
// One wave per batch row; lane i owns float4 #i of the 256-float row.
// Gathered rows are staged into LDS via global_load_lds (16 B/lane = 1 KB
// row per instruction, no data VGPRs), double-buffered in chunks of 4 rows,
// pipelined with explicit s_waitcnt vmcnt(4) so 8 row-gathers stay in
// flight per wave. 32 KB LDS/block -> 5 blocks/CU, 20 waves/CU.

constexpr int K  = 32;
constexpr int D  = 256;
constexpr int D4 = D / 4;           // 64 float4 per row == one per lane
constexpr int CHUNK  = 4;           // rows per DMA chunk
constexpr int NCHUNK = K / CHUNK;   // 8

#define AS1 __attribute__((address_space(1)))
#define AS3 __attribute__((address_space(3)))

__device__ __forceinline__ void dma_row_16B_per_lane(const float* gp, float* lp) {
    // lane i's 16 B land at lp + i*16 (wave-uniform LDS base + lane*size)
    __builtin_amdgcn_global_load_lds((const AS1 void*)gp, (AS3 void*)lp, 16, 0, 0);
}

__global__ __launch_bounds__(256) void gnn_agg_kernel(
    const int* __restrict__ neigh_ids,    // [B, K]
    const float* __restrict__ features,   // [N, D]
    float* __restrict__ out,              // [B, D]
    int n_rows)
{
    __shared__ __align__(16) float smem[4][2][CHUNK][D];   // 4 waves x dbuf x 4 rows x 1KB = 32 KB
    const int w    = threadIdx.x >> 6;
    const int lane = threadIdx.x & 63;

    const float4* __restrict__ f4 = reinterpret_cast<const float4*>(features);
    float4* __restrict__ o4       = reinterpret_cast<float4*>(out);

    for (int row = (int)blockIdx.x * 4 + w; row < n_rows; row += (int)gridDim.x * 4) {
        // all lanes load all 32 ids (8 x int4, wave-uniform addresses -> broadcast)
        const int4* idp = reinterpret_cast<const int4*>(neigh_ids + (size_t)row * K);
        int4 idq[NCHUNK];
        #pragma unroll
        for (int c = 0; c < NCHUNK; ++c) idq[c] = idp[c];

        // prologue: issue chunk 0 into buffer 0
        {
            const int4 q = idq[0];
            dma_row_16B_per_lane((const float*)(f4 + (size_t)q.x * D4 + lane), &smem[w][0][0][0]);
            dma_row_16B_per_lane((const float*)(f4 + (size_t)q.y * D4 + lane), &smem[w][0][1][0]);
            dma_row_16B_per_lane((const float*)(f4 + (size_t)q.z * D4 + lane), &smem[w][0][2][0]);
            dma_row_16B_per_lane((const float*)(f4 + (size_t)q.w * D4 + lane), &smem[w][0][3][0]);
        }

        float4 acc = make_float4(0.f, 0.f, 0.f, 0.f);
        #pragma unroll
        for (int c = 0; c < NCHUNK; ++c) {
            if (c + 1 < NCHUNK) {
                // issue next chunk into the other buffer, then wait for current
                const int4 q  = idq[c + 1];
                const int b1  = (c + 1) & 1;
                dma_row_16B_per_lane((const float*)(f4 + (size_t)q.x * D4 + lane), &smem[w][b1][0][0]);
                dma_row_16B_per_lane((const float*)(f4 + (size_t)q.y * D4 + lane), &smem[w][b1][1][0]);
                dma_row_16B_per_lane((const float*)(f4 + (size_t)q.z * D4 + lane), &smem[w][b1][2][0]);
                dma_row_16B_per_lane((const float*)(f4 + (size_t)q.w * D4 + lane), &smem[w][b1][3][0]);
                // wait until only the 4 newest DMAs remain outstanding
                asm volatile("s_waitcnt vmcnt(4)" ::: "memory");
            } else {
                asm volatile("s_waitcnt vmcnt(0)" ::: "memory");
            }
            const int b = c & 1;
            #pragma unroll
            for (int k = 0; k < CHUNK; ++k) {
                const float4 v = reinterpret_cast<const float4*>(&smem[w][b][k][0])[lane];
                acc.x += v.x; acc.y += v.y; acc.z += v.z; acc.w += v.w;
            }
        }

        const float s = 1.0f / (float)K;
        float4 r;
        r.x = fmaxf(acc.x * s, 0.f);
        r.y = fmaxf(acc.y * s, 0.f);
        r.z = fmaxf(acc.z * s, 0.f);
        r.w = fmaxf(acc.w * s, 0.f);
        o4[(size_t)row * D4 + lane] = r;
    }
}

extern "C" void kernel_launch(void* const* d_in, const int* in_sizes, int n_in,
                              void* d_out, int out_size, void* d_ws, size_t ws_size,
                              hipStream_t stream) {
    const int*   neigh_ids = (const int*)d_in[0];     // [B, K] int32
    const float* features  = (const float*)d_in[1];   // [N, D] fp32
    float*       out       = (float*)d_out;           // [B, D] fp32

    const int n_rows = out_size / D;                  // B = 16384
    const int blocks = (n_rows + 3) / 4;              // 4 waves/block, 1 row/wave

    gnn_agg_kernel<<<blocks, 256, 0, stream>>>(neigh_ids, features, out, n_rows);
}